// Round 4
// baseline (648.494 us; speedup 1.0000x reference)
//
#include <hip/hip_runtime.h>

#define HIDDEN 4096
#define NH 32
#define NKV 8
#define HD 128
#define SKV 8192
#define S2 32            // key-range splits for attn (blocks per batch)
#define KPB 256          // keys per block = SKV / S2
#define BUF 4            // keys per LDS buffer (3-slot ring)
#define NT (KPB/BUF)     // 64 stage/compute iterations
#define NPART 32         // partials per (b,n) = S2
#define PSTRIDE 520      // 4 l (+4 pad) + 4*128 acc
#define SCALE 0.08838834764831845f

__device__ __forceinline__ float4 ld4(const float* p){ return *(const float4*)p; }

// async global->LDS, 16B per lane; LDS dest = wave-uniform base + lane*16
__device__ __forceinline__ void gll16(const float* g, float* l){
    __builtin_amdgcn_global_load_lds(
        (const __attribute__((address_space(1))) unsigned int*)g,
        (__attribute__((address_space(3))) unsigned int*)l,
        16, 0, 0);
}

// ---------------- GEMV partial: part[c][b][j] = sum_{i in chunk c} vec[b][i]*mat[i][j]
// grid (4 jb, 64 c), 256 threads. chunk = 64 rows.
__global__ __launch_bounds__(256) void gemv_part(const float* __restrict__ vec,
                                                 const float* __restrict__ mat,
                                                 float* __restrict__ part)
{
    const int jb  = blockIdx.x;          // 0..3
    const int c   = blockIdx.y;          // 0..63
    const int tid = threadIdx.x;
    const int j0  = jb*1024 + tid*4;

    __shared__ float hid[64*8];          // hid[i][b] : i-major so reads are 2x b128 broadcast
    {
        int t = tid;                     // 512 elems, 2 per thread
        int b0 = t >> 6, i0 = t & 63;
        hid[i0*8 + b0] = vec[(size_t)b0*HIDDEN + c*64 + i0];
        t += 256;
        int b1 = t >> 6, i1 = t & 63;
        hid[i1*8 + b1] = vec[(size_t)b1*HIDDEN + c*64 + i1];
    }
    __syncthreads();

    float4 acc[8];
#pragma unroll
    for (int b=0;b<8;b++) acc[b] = make_float4(0.f,0.f,0.f,0.f);

    const float* mp = mat + (size_t)c*64*HIDDEN + j0;
#pragma unroll 8
    for (int ii=0; ii<64; ii++) {
        float4 w  = ld4(mp + (size_t)ii*HIDDEN);
        float4 h0 = *(const float4*)&hid[ii*8];      // b0..3
        float4 h1 = *(const float4*)&hid[ii*8+4];    // b4..7
        acc[0].x += h0.x*w.x; acc[0].y += h0.x*w.y; acc[0].z += h0.x*w.z; acc[0].w += h0.x*w.w;
        acc[1].x += h0.y*w.x; acc[1].y += h0.y*w.y; acc[1].z += h0.y*w.z; acc[1].w += h0.y*w.w;
        acc[2].x += h0.z*w.x; acc[2].y += h0.z*w.y; acc[2].z += h0.z*w.z; acc[2].w += h0.z*w.w;
        acc[3].x += h0.w*w.x; acc[3].y += h0.w*w.y; acc[3].z += h0.w*w.z; acc[3].w += h0.w*w.w;
        acc[4].x += h1.x*w.x; acc[4].y += h1.x*w.y; acc[4].z += h1.x*w.z; acc[4].w += h1.x*w.w;
        acc[5].x += h1.y*w.x; acc[5].y += h1.y*w.y; acc[5].z += h1.y*w.z; acc[5].w += h1.y*w.w;
        acc[6].x += h1.z*w.x; acc[6].y += h1.z*w.y; acc[6].z += h1.z*w.z; acc[6].w += h1.z*w.w;
        acc[7].x += h1.w*w.x; acc[7].y += h1.w*w.y; acc[7].z += h1.w*w.z; acc[7].w += h1.w*w.w;
    }
#pragma unroll
    for (int b=0;b<8;b++)
        *(float4*)(part + ((size_t)(c*8+b))*HIDDEN + j0) = acc[b];
}

// ---------------- reduce q partials + RoPE
__global__ __launch_bounds__(256) void q_reduce_rope(const float* __restrict__ part,
                                                     const float* __restrict__ cosb,
                                                     const float* __restrict__ sinb,
                                                     float* __restrict__ q_rope)
{
    const int b    = blockIdx.x >> 5;
    const int jseg = blockIdx.x & 31;
    const int tid  = threadIdx.x;
    const int jl   = tid & 127;
    const int cg   = tid >> 7;

    float a = 0.f;
    const float* pp = part + (size_t)(cg*32*8 + b)*HIDDEN + jseg*128 + jl;
#pragma unroll 8
    for (int c=0;c<32;c++) a += pp[(size_t)c*8*HIDDEN];

    __shared__ float lds[256];
    __shared__ float sum[128];
    lds[tid] = a;
    __syncthreads();
    if (tid < 128) sum[tid] = lds[tid] + lds[tid+128];
    __syncthreads();
    if (tid < 128) {
        const int d = tid;
        float x = sum[d];
        float p = sum[d ^ 64];
        float cv = cosb[b*HD + d], sv = sinb[b*HD + d];
        float r = (d < 64) ? (x*cv - p*sv) : (x*cv + p*sv);
        q_rope[(size_t)b*HIDDEN + jseg*128 + d] = r;
    }
}

// ---------------- attention split kernel, counted-vmcnt ring pipeline.
// Block = (split, b): 512 threads = 8 waves; wave w owns kv-head n = w.
// Full 4KB K/V records staged contiguously into a 3-slot LDS ring via
// global_load_lds; per iter: s_waitcnt vmcnt(4) keeps next stage's loads
// in flight ACROSS the barrier (no vmcnt(0) drain).
__global__ __launch_bounds__(512) void attn_split(const float* __restrict__ qr,
                                                  const float* __restrict__ kc,
                                                  const float* __restrict__ vc,
                                                  float* __restrict__ part)
{
    const int split = blockIdx.x;        // 0..S2-1
    const int b     = blockIdx.y;        // 0..7
    const int tid   = threadIdx.x;
    const int wave  = tid >> 6;          // 0..7 == kv head
    const int lane  = tid & 63;
    const int kg    = lane >> 4;         // key within 4-key buffer
    const int dl    = lane & 15;

    __shared__ __align__(16) float bufK[3][BUF*1024];   // 3 x 16KB
    __shared__ __align__(16) float bufV[3][BUF*1024];   // 3 x 16KB  (96KB total)

    // q fragments for this wave's 4 q-heads (pre-scaled)
    float4 q1[4], q2[4];
    const float* qb = qr + ((size_t)b*NH + wave*4)*HD;
#pragma unroll
    for (int h=0;h<4;h++){
        float4 x = ld4(qb + h*HD + dl*4);
        float4 y = ld4(qb + h*HD + 64 + dl*4);
        q1[h] = make_float4(x.x*SCALE, x.y*SCALE, x.z*SCALE, x.w*SCALE);
        q2[h] = make_float4(y.x*SCALE, y.y*SCALE, y.z*SCALE, y.w*SCALE);
    }

    float l[4] = {0.f,0.f,0.f,0.f};
    float4 acc1[4], acc2[4];
#pragma unroll
    for (int h=0;h<4;h++){
        acc1[h] = make_float4(0.f,0.f,0.f,0.f);
        acc2[h] = make_float4(0.f,0.f,0.f,0.f);
    }

    // contiguous key records: [B][SKV][NKV*HD]
    const float* kbase = kc + ((size_t)b*SKV + (size_t)split*KPB)*(NKV*HD);
    const float* vbase = vc + ((size_t)b*SKV + (size_t)split*KPB)*(NKV*HD);

    const int woff = wave*256 + lane*4;  // per-lane float offset within an 8KB segment

    // stage tile t into ring slot s: 4 gll16 per wave (2 K + 2 V), 1KB each
#define STAGE(t_, s_) do { \
        const float* gk = kbase + (size_t)(t_)*(BUF*1024); \
        const float* gv = vbase + (size_t)(t_)*(BUF*1024); \
        gll16(gk + woff,        &bufK[s_][wave*256]);        \
        gll16(gk + 2048 + woff, &bufK[s_][2048 + wave*256]); \
        gll16(gv + woff,        &bufV[s_][wave*256]);        \
        gll16(gv + 2048 + woff, &bufV[s_][2048 + wave*256]); \
    } while (0)

    // prologue: 2 stages in flight (8 outstanding loads)
    STAGE(0, 0);
    STAGE(1, 1);

    int cur = 0;
    for (int t = 0; t < NT; ++t) {
        // tile t ready; keep tile t+1's 4 loads in flight across the barrier
        if (t == NT-1) asm volatile("s_waitcnt vmcnt(0)" ::: "memory");
        else           asm volatile("s_waitcnt vmcnt(4)" ::: "memory");
        __builtin_amdgcn_s_barrier();
        asm volatile("" ::: "memory");           // no memory-op motion across barrier
        __builtin_amdgcn_sched_barrier(0);       // rule #18 hardening: pin scheduler too

        // issue stage t+2 into the slot last read as tile t-1 (all waves done with it)
        if (t + 2 < NT) {
            int s2 = cur + 2; if (s2 >= 3) s2 -= 3;
            STAGE(t+2, s2);
        }

        // compute: 4 keys from current slot, this wave's head slice
        {
            const float* Kb = &bufK[cur][kg*1024 + wave*128];
            const float* Vb = &bufV[cur][kg*1024 + wave*128];
            float4 k1 = ld4(Kb + dl*4);
            float4 k2 = ld4(Kb + 64 + dl*4);
            float4 v1 = ld4(Vb + dl*4);
            float4 v2 = ld4(Vb + 64 + dl*4);
            float p[4];
#pragma unroll
            for (int h=0;h<4;h++){
                float sp = q1[h].x*k1.x + q1[h].y*k1.y + q1[h].z*k1.z + q1[h].w*k1.w
                         + q2[h].x*k2.x + q2[h].y*k2.y + q2[h].z*k2.z + q2[h].w*k2.w;
                sp += __shfl_xor(sp, 1);
                sp += __shfl_xor(sp, 2);
                sp += __shfl_xor(sp, 4);
                sp += __shfl_xor(sp, 8);
                p[h] = __expf(sp);
                l[h] += p[h];
            }
#pragma unroll
            for (int h=0;h<4;h++){
                float ph = p[h];
                acc1[h].x += ph*v1.x; acc1[h].y += ph*v1.y;
                acc1[h].z += ph*v1.z; acc1[h].w += ph*v1.w;
                acc2[h].x += ph*v2.x; acc2[h].y += ph*v2.y;
                acc2[h].z += ph*v2.z; acc2[h].w += ph*v2.w;
            }
        }

        cur = (cur == 2) ? 0 : cur + 1;
    }
#undef STAGE

    // combine the 4 key-groups within the wave (pure adds)
#pragma unroll
    for (int h=0;h<4;h++){
        float t;
        t = l[h];      t += __shfl_xor(t,16); t += __shfl_xor(t,32); l[h] = t;
        t = acc1[h].x; t += __shfl_xor(t,16); t += __shfl_xor(t,32); acc1[h].x = t;
        t = acc1[h].y; t += __shfl_xor(t,16); t += __shfl_xor(t,32); acc1[h].y = t;
        t = acc1[h].z; t += __shfl_xor(t,16); t += __shfl_xor(t,32); acc1[h].z = t;
        t = acc1[h].w; t += __shfl_xor(t,16); t += __shfl_xor(t,32); acc1[h].w = t;
        t = acc2[h].x; t += __shfl_xor(t,16); t += __shfl_xor(t,32); acc2[h].x = t;
        t = acc2[h].y; t += __shfl_xor(t,16); t += __shfl_xor(t,32); acc2[h].y = t;
        t = acc2[h].z; t += __shfl_xor(t,16); t += __shfl_xor(t,32); acc2[h].z = t;
        t = acc2[h].w; t += __shfl_xor(t,16); t += __shfl_xor(t,32); acc2[h].w = t;
    }

    // one partial per (b, n=wave, split)
    float* pb = part + ((size_t)((b*NKV + wave)*S2 + split))*PSTRIDE;
    if (lane == 0){
#pragma unroll
        for (int h=0;h<4;h++) pb[h] = l[h];
    }
    if (kg == 0){
#pragma unroll
        for (int h=0;h<4;h++){
            *(float4*)(pb + 8 + h*HD + dl*4)      = acc1[h];
            *(float4*)(pb + 8 + h*HD + 64 + dl*4) = acc2[h];
        }
    }
}

// ---------------- combine 32 partials per (b,n) + the single new RoPE'd key
__global__ __launch_bounds__(256) void attn_combine(const float* __restrict__ part,
                                                    const float* __restrict__ qr,
                                                    const float* __restrict__ knew,
                                                    const float* __restrict__ vnew,
                                                    const float* __restrict__ cosb,
                                                    const float* __restrict__ sinb,
                                                    float* __restrict__ attn_out)
{
    const int bn  = blockIdx.x;   // b*8 + n
    const int b   = bn >> 3;
    const int n   = bn & 7;
    const int tid = threadIdx.x;
    const int wave = tid >> 6;
    const int lane = tid & 63;
    const float* pp = part + (size_t)bn*NPART*PSTRIDE;

    __shared__ float sm[4];       // exp(score_newkey) per head
    __shared__ float lds_l[NPART*4];

    // phase 1a: preload l values (128 = 32 partials x 4 heads)
    if (tid < NPART*4)
        lds_l[tid] = pp[(size_t)(tid>>2)*PSTRIDE + (tid&3)];

    // phase 1b: new-key RoPE + score, wave w handles head h=w
    {
        const float* kn = knew + (size_t)bn*HD;
        const float* cb = cosb + (size_t)b*HD;
        const float* sb = sinb + (size_t)b*HD;
        const float* qh = qr + ((size_t)b*NH + n*4 + wave)*HD;
        float k_lo = kn[lane], k_hi = kn[lane+64];
        float kr1 = k_lo*cb[lane]    - k_hi*sb[lane];
        float kr2 = k_hi*cb[lane+64] + k_lo*sb[lane+64];
        float sp = (qh[lane]*kr1 + qh[lane+64]*kr2) * SCALE;
        sp += __shfl_xor(sp, 1);
        sp += __shfl_xor(sp, 2);
        sp += __shfl_xor(sp, 4);
        sp += __shfl_xor(sp, 8);
        sp += __shfl_xor(sp, 16);
        sp += __shfl_xor(sp, 32);
        if (lane == 0) sm[wave] = __expf(sp);
    }
    __syncthreads();

    const int o = tid*2;
    const int h = o >> 7;
    const int d = o & 127;
    const float wn = sm[h];
    float L = wn;
#pragma unroll 8
    for (int p=0; p<NPART; p++) L += lds_l[p*4+h];

    const float* vn = vnew + (size_t)bn*HD;
    float a0 = wn * vn[d];
    float a1 = wn * vn[d+1];
    const float* ap = pp + 8 + h*HD + d;
#pragma unroll 8
    for (int p=0; p<NPART; p++){
        float2 v = *(const float2*)(ap + (size_t)p*PSTRIDE);
        a0 += v.x; a1 += v.y;
    }
    const float inv = 1.f / L;
    float* op = attn_out + ((size_t)b*NH + n*4 + h)*HD + d;
    op[0] = a0*inv; op[1] = a1*inv;
}

// ---------------- reduce output-proj partials -> d_out
__global__ __launch_bounds__(256) void o_reduce(const float* __restrict__ part,
                                                float* __restrict__ out)
{
    const int b    = blockIdx.x >> 5;
    const int jseg = blockIdx.x & 31;
    const int tid  = threadIdx.x;
    const int jl   = tid & 127;
    const int cg   = tid >> 7;

    float a = 0.f;
    const float* pp = part + (size_t)(cg*32*8 + b)*HIDDEN + jseg*128 + jl;
#pragma unroll 8
    for (int c=0;c<32;c++) a += pp[(size_t)c*8*HIDDEN];

    __shared__ float lds[256];
    lds[tid] = a;
    __syncthreads();
    if (tid < 128)
        out[(size_t)b*HIDDEN + jseg*128 + tid] = lds[tid] + lds[tid+128];
}

extern "C" void kernel_launch(void* const* d_in, const int* in_sizes, int n_in,
                              void* d_out, int out_size, void* d_ws, size_t ws_size,
                              hipStream_t stream) {
    const float* hidden = (const float*)d_in[0];
    const float* wq     = (const float*)d_in[1];
    const float* wo     = (const float*)d_in[2];
    const float* cosb   = (const float*)d_in[3];
    const float* sinb   = (const float*)d_in[4];
    const float* knew   = (const float*)d_in[5];
    const float* vnew   = (const float*)d_in[6];
    const float* kc     = (const float*)d_in[7];
    const float* vc     = (const float*)d_in[8];
    float* out = (float*)d_out;

    float* ws        = (float*)d_ws;
    float* part      = ws;                    // 64*8*4096      = 2,097,152 floats
    float* q_rope    = ws + 2097152;          // 8*32*128       = 32,768
    float* attn_out  = q_rope + 32768;        // 8*32*128       = 32,768
    float* attn_part = attn_out + 32768;      // 64*32*520      = 1,064,960 floats

    // 1) q = hidden @ wq (partials over 64 i-chunks)
    gemv_part<<<dim3(4,64), 256, 0, stream>>>(hidden, wq, part);
    // 2) reduce + RoPE
    q_reduce_rope<<<256, 256, 0, stream>>>(part, cosb, sinb, q_rope);
    // 3) flash-decoding: ring-pipelined LDS staging, 8 kv-heads per block, 1 block/CU
    attn_split<<<dim3(S2, 8), 512, 0, stream>>>(q_rope, kc, vc, attn_part);
    // 4) combine splits + new key
    attn_combine<<<64, 256, 0, stream>>>(attn_part, q_rope, knew, vnew, cosb, sinb, attn_out);
    // 5) out = attn_out @ wo (partials)
    gemv_part<<<dim3(4,64), 256, 0, stream>>>(attn_out, wo, part);
    // 6) final reduce -> d_out
    o_reduce<<<256, 256, 0, stream>>>(part, out);
}

// Round 5
// 619.434 us; speedup vs baseline: 1.0469x; 1.0469x over previous
//
#include <hip/hip_runtime.h>

#define HIDDEN 4096
#define NH 32
#define NKV 8
#define HD 128
#define SKV 8192
#define S2 64            // key-range splits for attn (blocks per batch)
#define KPB 128          // keys per block = SKV / S2
#define BUF 4            // keys per LDS buffer (double-buffered)
#define NT (KPB/BUF)     // 32 stage/compute iterations
#define NPART 64         // partials per (b,n) = S2
#define PSTRIDE 520      // 4 l (+4 pad) + 4*128 acc
#define NCHUNK 128       // gemv K-split chunks (32 rows each)
#define SCALE 0.08838834764831845f

__device__ __forceinline__ float4 ld4(const float* p){ return *(const float4*)p; }

// async global->LDS, 16B per lane; LDS dest = wave-uniform base + lane*16
__device__ __forceinline__ void gll16(const float* g, float* l){
    __builtin_amdgcn_global_load_lds(
        (const __attribute__((address_space(1))) unsigned int*)g,
        (__attribute__((address_space(3))) unsigned int*)l,
        16, 0, 0);
}

// ---------------- GEMV partial: part[c][b][j] = sum_{i in chunk c} vec[b][i]*mat[i][j]
// grid (4 jb, 128 c), 256 threads. chunk = 32 rows. 512 blocks = 2/CU, 8 waves/CU.
__global__ __launch_bounds__(256) void gemv_part(const float* __restrict__ vec,
                                                 const float* __restrict__ mat,
                                                 float* __restrict__ part)
{
    const int jb  = blockIdx.x;          // 0..3
    const int c   = blockIdx.y;          // 0..127
    const int tid = threadIdx.x;
    const int j0  = jb*1024 + tid*4;

    __shared__ float hid[32*8];          // hid[i][b] : i-major so reads are 2x b128 broadcast
    {
        int b0 = tid >> 5, i0 = tid & 31;   // 256 elems, 1 per thread
        hid[i0*8 + b0] = vec[(size_t)b0*HIDDEN + c*32 + i0];
    }
    __syncthreads();

    float4 acc[8];
#pragma unroll
    for (int b=0;b<8;b++) acc[b] = make_float4(0.f,0.f,0.f,0.f);

    const float* mp = mat + (size_t)c*32*HIDDEN + j0;
#pragma unroll 8
    for (int ii=0; ii<32; ii++) {
        float4 w  = ld4(mp + (size_t)ii*HIDDEN);
        float4 h0 = *(const float4*)&hid[ii*8];      // b0..3
        float4 h1 = *(const float4*)&hid[ii*8+4];    // b4..7
        acc[0].x += h0.x*w.x; acc[0].y += h0.x*w.y; acc[0].z += h0.x*w.z; acc[0].w += h0.x*w.w;
        acc[1].x += h0.y*w.x; acc[1].y += h0.y*w.y; acc[1].z += h0.y*w.z; acc[1].w += h0.y*w.w;
        acc[2].x += h0.z*w.x; acc[2].y += h0.z*w.y; acc[2].z += h0.z*w.z; acc[2].w += h0.z*w.w;
        acc[3].x += h0.w*w.x; acc[3].y += h0.w*w.y; acc[3].z += h0.w*w.z; acc[3].w += h0.w*w.w;
        acc[4].x += h1.x*w.x; acc[4].y += h1.x*w.y; acc[4].z += h1.x*w.z; acc[4].w += h1.x*w.w;
        acc[5].x += h1.y*w.x; acc[5].y += h1.y*w.y; acc[5].z += h1.y*w.z; acc[5].w += h1.y*w.w;
        acc[6].x += h1.z*w.x; acc[6].y += h1.z*w.y; acc[6].z += h1.z*w.z; acc[6].w += h1.z*w.w;
        acc[7].x += h1.w*w.x; acc[7].y += h1.w*w.y; acc[7].z += h1.w*w.z; acc[7].w += h1.w*w.w;
    }
#pragma unroll
    for (int b=0;b<8;b++)
        *(float4*)(part + ((size_t)(c*8+b))*HIDDEN + j0) = acc[b];
}

// ---------------- reduce q partials + RoPE (128 chunks)
// grid (8b * 32 jseg) = 256 blocks, 256 thr = 128 j x 2 cg (64 chunks each)
__global__ __launch_bounds__(256) void q_reduce_rope(const float* __restrict__ part,
                                                     const float* __restrict__ cosb,
                                                     const float* __restrict__ sinb,
                                                     float* __restrict__ q_rope)
{
    const int b    = blockIdx.x >> 5;
    const int jseg = blockIdx.x & 31;
    const int tid  = threadIdx.x;
    const int jl   = tid & 127;
    const int cg   = tid >> 7;

    float a = 0.f;
    const float* pp = part + (size_t)(cg*64*8 + b)*HIDDEN + jseg*128 + jl;
#pragma unroll 8
    for (int c=0;c<64;c++) a += pp[(size_t)c*8*HIDDEN];

    __shared__ float lds[256];
    __shared__ float sum[128];
    lds[tid] = a;
    __syncthreads();
    if (tid < 128) sum[tid] = lds[tid] + lds[tid+128];
    __syncthreads();
    if (tid < 128) {
        const int d = tid;
        float x = sum[d];
        float p = sum[d ^ 64];
        float cv = cosb[b*HD + d], sv = sinb[b*HD + d];
        float r = (d < 64) ? (x*cv - p*sv) : (x*cv + p*sv);
        q_rope[(size_t)b*HIDDEN + jseg*128 + d] = r;
    }
}

// ---------------- attention split kernel (round-2 winner structure).
// Block = (split, b): 512 threads = 8 waves; wave w owns kv-head n = w.
// Full 4KB K/V records staged contiguously into LDS (all channel phases),
// compute reads per-head slices from LDS. Double-buffered, 4 keys/buffer.
__global__ __launch_bounds__(512) void attn_split(const float* __restrict__ qr,
                                                  const float* __restrict__ kc,
                                                  const float* __restrict__ vc,
                                                  float* __restrict__ part)
{
    const int split = blockIdx.x;        // 0..S2-1
    const int b     = blockIdx.y;        // 0..7
    const int tid   = threadIdx.x;
    const int wave  = tid >> 6;          // 0..7 == kv head
    const int lane  = tid & 63;
    const int kg    = lane >> 4;         // key within 4-key buffer
    const int dl    = lane & 15;

    __shared__ __align__(16) float bufK[2][BUF*1024];   // 16KB each
    __shared__ __align__(16) float bufV[2][BUF*1024];

    // q fragments for this wave's 4 q-heads (pre-scaled)
    float4 q1[4], q2[4];
    const float* qb = qr + ((size_t)b*NH + wave*4)*HD;
#pragma unroll
    for (int h=0;h<4;h++){
        float4 x = ld4(qb + h*HD + dl*4);
        float4 y = ld4(qb + h*HD + 64 + dl*4);
        q1[h] = make_float4(x.x*SCALE, x.y*SCALE, x.z*SCALE, x.w*SCALE);
        q2[h] = make_float4(y.x*SCALE, y.y*SCALE, y.z*SCALE, y.w*SCALE);
    }

    float l[4] = {0.f,0.f,0.f,0.f};
    float4 acc1[4], acc2[4];
#pragma unroll
    for (int h=0;h<4;h++){
        acc1[h] = make_float4(0.f,0.f,0.f,0.f);
        acc2[h] = make_float4(0.f,0.f,0.f,0.f);
    }

    // contiguous key records: [B][SKV][NKV*HD]
    const float* kbase = kc + ((size_t)b*SKV + (size_t)split*KPB)*(NKV*HD);
    const float* vbase = vc + ((size_t)b*SKV + (size_t)split*KPB)*(NKV*HD);

    const int woff = wave*256 + lane*4;  // per-lane float offset within an 8KB segment

    // ---- prologue: stage tile 0 into buffer 0
    {
        const float* gk = kbase;
        const float* gv = vbase;
        gll16(gk + woff,        &bufK[0][wave*256]);
        gll16(gk + 2048 + woff, &bufK[0][2048 + wave*256]);
        gll16(gv + woff,        &bufV[0][wave*256]);
        gll16(gv + 2048 + woff, &bufV[0][2048 + wave*256]);
    }
    __syncthreads();

    int cur = 0;
    for (int t = 0; t < NT; ++t) {
        // stage next tile into the other buffer (flight hidden under compute)
        if (t + 1 < NT) {
            const float* gk = kbase + (size_t)(t+1)*(BUF*1024);
            const float* gv = vbase + (size_t)(t+1)*(BUF*1024);
            const int nb = cur ^ 1;
            gll16(gk + woff,        &bufK[nb][wave*256]);
            gll16(gk + 2048 + woff, &bufK[nb][2048 + wave*256]);
            gll16(gv + woff,        &bufV[nb][wave*256]);
            gll16(gv + 2048 + woff, &bufV[nb][2048 + wave*256]);
        }

        // compute: 4 keys from current buffer, this wave's head slice
        {
            const float* Kb = &bufK[cur][kg*1024 + wave*128];
            const float* Vb = &bufV[cur][kg*1024 + wave*128];
            float4 k1 = ld4(Kb + dl*4);
            float4 k2 = ld4(Kb + 64 + dl*4);
            float4 v1 = ld4(Vb + dl*4);
            float4 v2 = ld4(Vb + 64 + dl*4);
            float p[4];
#pragma unroll
            for (int h=0;h<4;h++){
                float sp = q1[h].x*k1.x + q1[h].y*k1.y + q1[h].z*k1.z + q1[h].w*k1.w
                         + q2[h].x*k2.x + q2[h].y*k2.y + q2[h].z*k2.z + q2[h].w*k2.w;
                sp += __shfl_xor(sp, 1);
                sp += __shfl_xor(sp, 2);
                sp += __shfl_xor(sp, 4);
                sp += __shfl_xor(sp, 8);
                p[h] = __expf(sp);
                l[h] += p[h];
            }
#pragma unroll
            for (int h=0;h<4;h++){
                float ph = p[h];
                acc1[h].x += ph*v1.x; acc1[h].y += ph*v1.y;
                acc1[h].z += ph*v1.z; acc1[h].w += ph*v1.w;
                acc2[h].x += ph*v2.x; acc2[h].y += ph*v2.y;
                acc2[h].z += ph*v2.z; acc2[h].w += ph*v2.w;
            }
        }

        __syncthreads();   // drains vmcnt (next buffer ready) + protects overwrite
        cur ^= 1;
    }

    // combine the 4 key-groups within the wave (pure adds)
#pragma unroll
    for (int h=0;h<4;h++){
        float t;
        t = l[h];      t += __shfl_xor(t,16); t += __shfl_xor(t,32); l[h] = t;
        t = acc1[h].x; t += __shfl_xor(t,16); t += __shfl_xor(t,32); acc1[h].x = t;
        t = acc1[h].y; t += __shfl_xor(t,16); t += __shfl_xor(t,32); acc1[h].y = t;
        t = acc1[h].z; t += __shfl_xor(t,16); t += __shfl_xor(t,32); acc1[h].z = t;
        t = acc1[h].w; t += __shfl_xor(t,16); t += __shfl_xor(t,32); acc1[h].w = t;
        t = acc2[h].x; t += __shfl_xor(t,16); t += __shfl_xor(t,32); acc2[h].x = t;
        t = acc2[h].y; t += __shfl_xor(t,16); t += __shfl_xor(t,32); acc2[h].y = t;
        t = acc2[h].z; t += __shfl_xor(t,16); t += __shfl_xor(t,32); acc2[h].z = t;
        t = acc2[h].w; t += __shfl_xor(t,16); t += __shfl_xor(t,32); acc2[h].w = t;
    }

    // one partial per (b, n=wave, split)
    float* pb = part + ((size_t)((b*NKV + wave)*S2 + split))*PSTRIDE;
    if (lane == 0){
#pragma unroll
        for (int h=0;h<4;h++) pb[h] = l[h];
    }
    if (kg == 0){
#pragma unroll
        for (int h=0;h<4;h++){
            *(float4*)(pb + 8 + h*HD + dl*4)      = acc1[h];
            *(float4*)(pb + 8 + h*HD + 64 + dl*4) = acc2[h];
        }
    }
}

// ---------------- combine 64 partials per (b,n) + the single new RoPE'd key
__global__ __launch_bounds__(256) void attn_combine(const float* __restrict__ part,
                                                    const float* __restrict__ qr,
                                                    const float* __restrict__ knew,
                                                    const float* __restrict__ vnew,
                                                    const float* __restrict__ cosb,
                                                    const float* __restrict__ sinb,
                                                    float* __restrict__ attn_out)
{
    const int bn  = blockIdx.x;   // b*8 + n
    const int b   = bn >> 3;
    const int n   = bn & 7;
    const int tid = threadIdx.x;
    const int wave = tid >> 6;
    const int lane = tid & 63;
    const float* pp = part + (size_t)bn*NPART*PSTRIDE;

    __shared__ float sm[4];       // exp(score_newkey) per head
    __shared__ float lds_l[NPART*4];

    // phase 1a: preload l values (256 = 64 partials x 4 heads)
    lds_l[tid] = pp[(size_t)(tid>>2)*PSTRIDE + (tid&3)];

    // phase 1b: new-key RoPE + score, wave w handles head h=w
    {
        const float* kn = knew + (size_t)bn*HD;
        const float* cb = cosb + (size_t)b*HD;
        const float* sb = sinb + (size_t)b*HD;
        const float* qh = qr + ((size_t)b*NH + n*4 + wave)*HD;
        float k_lo = kn[lane], k_hi = kn[lane+64];
        float kr1 = k_lo*cb[lane]    - k_hi*sb[lane];
        float kr2 = k_hi*cb[lane+64] + k_lo*sb[lane+64];
        float sp = (qh[lane]*kr1 + qh[lane+64]*kr2) * SCALE;
        sp += __shfl_xor(sp, 1);
        sp += __shfl_xor(sp, 2);
        sp += __shfl_xor(sp, 4);
        sp += __shfl_xor(sp, 8);
        sp += __shfl_xor(sp, 16);
        sp += __shfl_xor(sp, 32);
        if (lane == 0) sm[wave] = __expf(sp);
    }
    __syncthreads();

    const int o = tid*2;
    const int h = o >> 7;
    const int d = o & 127;
    const float wn = sm[h];
    float L = wn;
#pragma unroll 8
    for (int p=0; p<NPART; p++) L += lds_l[p*4+h];

    const float* vn = vnew + (size_t)bn*HD;
    float a0 = wn * vn[d];
    float a1 = wn * vn[d+1];
    const float* ap = pp + 8 + h*HD + d;
#pragma unroll 8
    for (int p=0; p<NPART; p++){
        float2 v = *(const float2*)(ap + (size_t)p*PSTRIDE);
        a0 += v.x; a1 += v.y;
    }
    const float inv = 1.f / L;
    float* op = attn_out + ((size_t)b*NH + n*4 + h)*HD + d;
    op[0] = a0*inv; op[1] = a1*inv;
}

// ---------------- reduce output-proj partials -> d_out (128 chunks)
__global__ __launch_bounds__(256) void o_reduce(const float* __restrict__ part,
                                                float* __restrict__ out)
{
    const int b    = blockIdx.x >> 5;
    const int jseg = blockIdx.x & 31;
    const int tid  = threadIdx.x;
    const int jl   = tid & 127;
    const int cg   = tid >> 7;

    float a = 0.f;
    const float* pp = part + (size_t)(cg*64*8 + b)*HIDDEN + jseg*128 + jl;
#pragma unroll 8
    for (int c=0;c<64;c++) a += pp[(size_t)c*8*HIDDEN];

    __shared__ float lds[256];
    lds[tid] = a;
    __syncthreads();
    if (tid < 128)
        out[(size_t)b*HIDDEN + jseg*128 + tid] = lds[tid] + lds[tid+128];
}

extern "C" void kernel_launch(void* const* d_in, const int* in_sizes, int n_in,
                              void* d_out, int out_size, void* d_ws, size_t ws_size,
                              hipStream_t stream) {
    const float* hidden = (const float*)d_in[0];
    const float* wq     = (const float*)d_in[1];
    const float* wo     = (const float*)d_in[2];
    const float* cosb   = (const float*)d_in[3];
    const float* sinb   = (const float*)d_in[4];
    const float* knew   = (const float*)d_in[5];
    const float* vnew   = (const float*)d_in[6];
    const float* kc     = (const float*)d_in[7];
    const float* vc     = (const float*)d_in[8];
    float* out = (float*)d_out;

    float* ws        = (float*)d_ws;
    float* part      = ws;                    // 128*8*4096     = 4,194,304 floats
    float* q_rope    = ws + 4194304;          // 8*32*128       = 32,768
    float* attn_out  = q_rope + 32768;        // 8*32*128       = 32,768
    float* attn_part = attn_out + 32768;      // 64*64*520      = 2,129,920 floats

    // 1) q = hidden @ wq (partials over 128 i-chunks)
    gemv_part<<<dim3(4,128), 256, 0, stream>>>(hidden, wq, part);
    // 2) reduce + RoPE
    q_reduce_rope<<<256, 256, 0, stream>>>(part, cosb, sinb, q_rope);
    // 3) flash-decoding: contiguous-record LDS staging, 8 kv-heads per block, 2 blocks/CU
    attn_split<<<dim3(S2, 8), 512, 0, stream>>>(q_rope, kc, vc, attn_part);
    // 4) combine splits + new key
    attn_combine<<<64, 256, 0, stream>>>(attn_part, q_rope, knew, vnew, cosb, sinb, attn_out);
    // 5) out = attn_out @ wo (partials)
    gemv_part<<<dim3(4,128), 256, 0, stream>>>(attn_out, wo, part);
    // 6) final reduce -> d_out
    o_reduce<<<256, 256, 0, stream>>>(part, out);
}